// Round 4
// baseline (114.635 us; speedup 1.0000x reference)
//
#include <hip/hip_runtime.h>
#include <math.h>

// One block (512 threads) per video row. T = 4096 = 512 chunks x 8. DELTA=16 = 2 chunks.
// Thread j owns chunk j (t in [8j, 8j+8)): loads it as float4s, keeps z[8] + p1m[8] in
// registers, computes chunk maxima in registers, stores masked p1 to LDS (p2 = 1-p1
// recomputed on read). Prefix/suffix cummax over 512 chunk maxima via wave shuffles +
// 8-wave LDS combine. Block results accumulate straight into d_out via fp32 atomics
// (out zeroed by a tiny memsetAsync) — no second reduce dispatch.

#define T_LEN 4096
#define NTH   512
#define CH    8
#define PADS  9        // padded chunk stride: bank (9j+i)%32 covers all banks (9 coprime 32)
#define DELTA 16
#define NEGV  (-1e30f)
#define NEGH  (-5e29f)

__device__ __forceinline__ float frcp(float x) { return __builtin_amdgcn_rcpf(x); }

__device__ __forceinline__ void amax_comb(float& v, int& i, float ov, int oi) {
  // argmax, first-occurrence (smallest index) tie-break — matches jnp.argmax
  if (ov > v || (ov == v && oi < i)) { v = ov; i = oi; }
}

__global__ __launch_bounds__(512, 4) void lftc_main(
    const float* __restrict__ s1s2,  // [B, T, 2]
    const float* __restrict__ act,   // [B, T]
    const int*   __restrict__ lens,  // [B]
    const float* __restrict__ vls,   // [B]
    float* __restrict__ out)         // [2]: {state_sum, 0.2*action_sum}, pre-zeroed
{
  __shared__ float P1s[NTH * PADS];  // masked p1 (p2 = 1-p1 where valid)
  __shared__ float cm1[NTH];         // inclusive prefix-max of chunk p1-maxima
  __shared__ float cm2[NTH];         // inclusive suffix-max of chunk p2-maxima
  __shared__ float wag1[8], wag2[8];
  __shared__ float redv[8];  __shared__ int redi[8];   // ac argmax
  __shared__ float redv2[8]; __shared__ int redi2[8];  // s1 argmax
  __shared__ float redv3[8]; __shared__ int redi3[8];  // s2 argmax

  const int b    = blockIdx.x;
  const int tid  = threadIdx.x;
  const int lane = tid & 63;
  const int wv   = tid >> 6;         // 8 waves
  const int len  = lens[b];
  const float w  = vls[b];

  const float* __restrict__ srow = s1s2 + (size_t)b * T_LEN * 2;
  const float* __restrict__ zrow = act  + (size_t)b * T_LEN;

  const int j    = tid;
  const int base = j * CH;

  // ---------- phase 1: batch-load chunk, softmax via single exp, chunk maxima ----------
  float4 sv[4];
  {
    const float4* sp4 = reinterpret_cast<const float4*>(srow + 2 * base);
#pragma unroll
    for (int k = 0; k < 4; k++) sv[k] = sp4[k];
  }
  float4 zv[2];
  {
    const float4* zp4 = reinterpret_cast<const float4*>(zrow + base);
    zv[0] = zp4[0]; zv[1] = zp4[1];
  }
  const float* sf = reinterpret_cast<const float*>(sv);
  const float* z  = reinterpret_cast<const float*>(zv);

  float p1r[CH];                     // own masked p1, kept in registers
  float m1 = NEGV, m2 = NEGV, sp_part = 0.f;
#pragma unroll
  for (int i = 0; i < CH; i++) {
    float lx = sf[2 * i], ly = sf[2 * i + 1];
    float p  = frcp(1.f + __expf(ly - lx));       // p1 = softmax[...,0]
    bool  v  = (base + i) < len;
    float p1m = v ? p : NEGV;
    float p2m = v ? 1.f - p : NEGV;
    p1r[i] = p1m;
    P1s[j * PADS + i] = p1m;
    m1 = fmaxf(m1, p1m);
    m2 = fmaxf(m2, p2m);
    float zi = z[i];
    if (v) sp_part += fmaxf(zi, 0.f) + __logf(1.f + __expf(-fabsf(zi)));  // softplus(z)
  }

  // ---------- phase 2: prefix-max (m1) + suffix-max (m2) scans over 512 chunks ----------
  {
    float pm = m1;
#pragma unroll
    for (int off = 1; off < 64; off <<= 1) {
      float o = __shfl_up(pm, off);
      if (lane >= off) pm = fmaxf(pm, o);
    }
    float sm = m2;
#pragma unroll
    for (int off = 1; off < 64; off <<= 1) {
      float o = __shfl_down(sm, off);
      if (lane + off < 64) sm = fmaxf(sm, o);
    }
    if (lane == 63) wag1[wv] = pm;   // wave total (prefix side)
    if (lane == 0)  wag2[wv] = sm;   // wave total (suffix side)
    __syncthreads();
    float addp = NEGV, adds = NEGV;
#pragma unroll
    for (int q = 0; q < 8; q++) {
      if (q < wv) addp = fmaxf(addp, wag1[q]);
      if (q > wv) adds = fmaxf(adds, wag2[q]);
    }
    cm1[tid] = fmaxf(pm, addp);
    cm2[tid] = fmaxf(sm, adds);
    __syncthreads();   // also publishes P1s
  }

  // ---------- phase 3: score[t] = pre[t-16] * sigmoid(z[t]) * suf[t+16]; argmax -> ac ----
  float best = NEGV;
  int   bidx = base;    // all-masked rows reduce to index 0 (matches jnp.argmax)
  {
    float rs[CH];       // suf_s for this chunk: reverse scan over chunk j+2
    if (j <= NTH - 3) {
      float run = (j + 3 <= NTH - 1) ? cm2[j + 3] : NEGV;
      const int b2 = (j + 2) * PADS;
#pragma unroll
      for (int i = CH - 1; i >= 0; --i) {
        float p1n = P1s[b2 + i];
        float p2n = (p1n > NEGH) ? 1.f - p1n : NEGV;
        run = fmaxf(run, p2n);
        rs[i] = run;
      }
    }
    float prerun = (j >= 3) ? cm1[j - 3] : NEGV;   // chunks [0 .. j-3]
    const int b1 = (j - 2) * PADS;
#pragma unroll
    for (int i = 0; i < CH; i++) {
      float pre_s = NEGV;
      if (j >= 2) { prerun = fmaxf(prerun, P1s[b1 + i]); pre_s = prerun; }
      float suf_s = (j <= NTH - 3) ? rs[i] : NEGV;
      int t = base + i;
      if (pre_s > NEGH && suf_s > NEGH && t < len) {
        float pa = frcp(1.f + __expf(-z[i]));
        float sc = (pre_s * pa) * suf_s;
        if (sc > best) { best = sc; bidx = t; }   // strict > keeps first occurrence
      }
    }
  }
#pragma unroll
  for (int off = 32; off; off >>= 1) {
    float ov = __shfl_down(best, off);
    int   oi = __shfl_down(bidx, off);
    amax_comb(best, bidx, ov, oi);
  }
  if (lane == 0) { redv[wv] = best; redi[wv] = bidx; }
  __syncthreads();
  int ac;
  {
    // redundant final combine in every thread: saves a barrier + tid0 serialization
    float v = redv[0]; int i = redi[0];
#pragma unroll
    for (int q = 1; q < 8; q++) amax_comb(v, i, redv[q], redi[q]);
    ac = i;
  }

  // ---------- phase 4: s1 = argmax p1m on [0, ac-16]; s2 = argmax p2m on [ac+16, T) ----
  {
    float v1 = NEGV; int i1 = 0;
    float v2 = NEGV; int i2 = 0;
    const int e1   = ac - DELTA;
    const int s2lo = ac + DELTA;
#pragma unroll
    for (int k = 0; k < CH; k++) {
      int t = base + k;
      float p1v = p1r[k];
      if (t <= e1 && p1v > v1) { v1 = p1v; i1 = t; }
      float p2v = (p1v > NEGH) ? 1.f - p1v : NEGV;
      if (t >= s2lo && p2v > v2) { v2 = p2v; i2 = t; }
    }
#pragma unroll
    for (int off = 32; off; off >>= 1) {
      float ov1 = __shfl_down(v1, off); int oi1 = __shfl_down(i1, off);
      amax_comb(v1, i1, ov1, oi1);
      float ov2 = __shfl_down(v2, off); int oi2 = __shfl_down(i2, off);
      amax_comb(v2, i2, ov2, oi2);
    }
    if (lane == 0) { redv2[wv] = v1; redi2[wv] = i1; redv3[wv] = v2; redi3[wv] = i2; }
  }

  // ---------- phase 5: action window correction (from registers) + block sum + output --
  // window: positions with |t-ac| <= 4 and valid get 10*softplus(-z) instead of softplus(z)
#pragma unroll
  for (int k = 0; k < CH; k++) {
    int t = base + k;
    int d = t - ac;
    if (d >= -4 && d <= 4 && t < len) {
      float zi = z[k];
      float b0 = fmaxf(zi, 0.f) + __logf(1.f + __expf(-fabsf(zi)));  // softplus(z)
      sp_part += 10.f * (b0 - zi) - b0;
    }
  }
  float s = sp_part;
#pragma unroll
  for (int off = 32; off; off >>= 1) s += __shfl_down(s, off);
  if (lane == 0) wag1[wv] = s;   // safe: last wag1 read precedes phase-3's barrier
  __syncthreads();
  if (tid == 0) {
    float tot = 0.f;
#pragma unroll
    for (int q = 0; q < 8; q++) tot += wag1[q];

    float sv1 = redv2[0]; int s1 = redi2[0];
    float sv2 = redv3[0]; int s2 = redi3[0];
    for (int q = 1; q < 8; q++) {
      amax_comb(sv1, s1, redv2[q], redi2[q]);
      amax_comb(sv2, s2, redv3[q], redi3[q]);
    }
    // state CE: -log_softmax[s1,0] = softplus(l1-l0); -log_softmax[s2,1] = softplus(l0-l1)
    float a0 = srow[2 * (size_t)s1], a1 = srow[2 * (size_t)s1 + 1];
    float c0 = srow[2 * (size_t)s2], c1 = srow[2 * (size_t)s2 + 1];
    float d1 = a1 - a0;
    float loss1 = fmaxf(d1, 0.f) + __logf(1.f + __expf(-fabsf(d1)));
    float d2 = c0 - c1;
    float loss2 = fmaxf(d2, 0.f) + __logf(1.f + __expf(-fabsf(d2)));

    atomicAdd(out + 0, w * (loss1 + loss2));          // ~1024 adds/address, L2 atomic
    atomicAdd(out + 1, 0.2f * w * tot);               // unit pipelines them (~µs tail)
  }
}

extern "C" void kernel_launch(void* const* d_in, const int* in_sizes, int n_in,
                              void* d_out, int out_size, void* d_ws, size_t ws_size,
                              hipStream_t stream) {
  const float* s1s2 = (const float*)d_in[0];
  const float* act  = (const float*)d_in[1];
  const int*   lens = (const int*)d_in[2];
  const float* vls  = (const float*)d_in[3];
  float* out = (float*)d_out;

  const int B = in_sizes[2];   // lens has B elements; T fixed at 4096

  hipMemsetAsync(out, 0, (size_t)out_size * sizeof(float), stream);
  lftc_main<<<B, NTH, 0, stream>>>(s1s2, act, lens, vls, out);
}

// Round 5
// 108.601 us; speedup vs baseline: 1.0556x; 1.0556x over previous
//
#include <hip/hip_runtime.h>
#include <math.h>

// One block (1024 threads = 16 waves) per video row. T = 4096 = 1024 chunks x 4.
// DELTA=16 = 4 chunks. Thread j owns chunk j (t in [4j, 4j+4)): loads it as float4s,
// keeps z[4] + masked p1[4] in registers, stores masked p1 to LDS (p2 = 1-p1 on read).
// Prefix/suffix cummax over 1024 chunk maxima via wave shuffles + 16-wave LDS combine.
// launch_bounds(1024,8): 2 blocks/CU = 32 waves/CU (full occupancy), VGPR cap 64.
// Per-block partials -> d_ws; tiny second kernel reduces (R4 showed same-address
// fp32 atomic storm costs ~15us tail — do NOT accumulate d_out with atomics).

#define T_LEN 4096
#define NTH   1024
#define NW    16       // waves per block
#define CH    4
#define PADS  5        // chunk stride 5 words: 5 coprime 32 -> 2-way/bank max = free
#define DCH   4        // DELTA / CH
#define DELTA 16
#define NEGV  (-1e30f)
#define NEGH  (-5e29f)

__device__ __forceinline__ float frcp(float x) { return __builtin_amdgcn_rcpf(x); }

__device__ __forceinline__ void amax_comb(float& v, int& i, float ov, int oi) {
  // argmax, first-occurrence (smallest index) tie-break — matches jnp.argmax
  if (ov > v || (ov == v && oi < i)) { v = ov; i = oi; }
}

__global__ __launch_bounds__(NTH, 8) void lftc_main(
    const float* __restrict__ s1s2,  // [B, T, 2]
    const float* __restrict__ act,   // [B, T]
    const int*   __restrict__ lens,  // [B]
    const float* __restrict__ vls,   // [B]
    float* __restrict__ ws)          // [B, 2]: {state_partial, action_partial}
{
  __shared__ float P1s[NTH * PADS];  // masked p1 (p2 = 1-p1 where valid)
  __shared__ float cm1[NTH];         // inclusive prefix-max of chunk p1-maxima
  __shared__ float cm2[NTH];         // inclusive suffix-max of chunk p2-maxima
  __shared__ float wag1[NW], wag2[NW];
  __shared__ float redv[NW];  __shared__ int redi[NW];   // ac argmax
  __shared__ float redv2[NW]; __shared__ int redi2[NW];  // s1 argmax
  __shared__ float redv3[NW]; __shared__ int redi3[NW];  // s2 argmax

  const int b    = blockIdx.x;
  const int tid  = threadIdx.x;
  const int lane = tid & 63;
  const int wv   = tid >> 6;
  const int len  = lens[b];

  const float* __restrict__ srow = s1s2 + (size_t)b * T_LEN * 2;
  const float* __restrict__ zrow = act  + (size_t)b * T_LEN;

  const int j    = tid;
  const int base = j * CH;

  // ---------- phase 1 (short pre-barrier path): load, softmax, mask, LDS store ----------
  float4 sv0, sv1, zv;
  {
    const float4* sp4 = reinterpret_cast<const float4*>(srow + 2 * base);
    sv0 = sp4[0]; sv1 = sp4[1];
    zv  = *reinterpret_cast<const float4*>(zrow + base);
  }
  float z[CH]   = {zv.x, zv.y, zv.z, zv.w};
  float lx[CH]  = {sv0.x, sv0.z, sv1.x, sv1.z};
  float ly[CH]  = {sv0.y, sv0.w, sv1.y, sv1.w};

  float p1r[CH];
  float m1 = NEGV, m2 = NEGV;
#pragma unroll
  for (int i = 0; i < CH; i++) {
    float p   = frcp(1.f + __expf(ly[i] - lx[i]));   // p1 = softmax[...,0]
    bool  v   = (base + i) < len;
    float p1m = v ? p : NEGV;
    float p2m = v ? 1.f - p : NEGV;
    p1r[i] = p1m;
    P1s[j * PADS + i] = p1m;
    m1 = fmaxf(m1, p1m);
    m2 = fmaxf(m2, p2m);
  }

  // ---------- phase 2: prefix-max (m1) + suffix-max (m2) scans over 1024 chunks ----------
  {
    float pm = m1;
#pragma unroll
    for (int off = 1; off < 64; off <<= 1) {
      float o = __shfl_up(pm, off);
      if (lane >= off) pm = fmaxf(pm, o);
    }
    float sm = m2;
#pragma unroll
    for (int off = 1; off < 64; off <<= 1) {
      float o = __shfl_down(sm, off);
      if (lane + off < 64) sm = fmaxf(sm, o);
    }
    if (lane == 63) wag1[wv] = pm;   // wave total (prefix side)
    if (lane == 0)  wag2[wv] = sm;   // wave total (suffix side)
    __syncthreads();                 // B1: publishes P1s + wave totals
    float addp = NEGV, adds = NEGV;
#pragma unroll
    for (int q = 0; q < NW; q++) {
      if (q < wv) addp = fmaxf(addp, wag1[q]);
      if (q > wv) adds = fmaxf(adds, wag2[q]);
    }
    cm1[tid] = fmaxf(pm, addp);
    cm2[tid] = fmaxf(sm, adds);
    __syncthreads();                 // B2
  }

  // ---------- phase 3: score[t] = pre[t-16] * sigmoid(z[t]) * suf[t+16]; argmax -> ac ----
  float best = NEGV;
  int   bidx = base;    // all-masked rows reduce to index 0 (matches jnp.argmax)
  {
    float rs[CH];       // suf_s for this chunk: reverse partial over chunk j+DCH
    if (j <= NTH - 1 - DCH) {
      float run = (j + DCH + 1 <= NTH - 1) ? cm2[j + DCH + 1] : NEGV;
      const int b2 = (j + DCH) * PADS;
#pragma unroll
      for (int i = CH - 1; i >= 0; --i) {
        float p1n = P1s[b2 + i];
        float p2n = (p1n > NEGH) ? 1.f - p1n : NEGV;
        run = fmaxf(run, p2n);
        rs[i] = run;
      }
    }
    float prerun = (j >= DCH + 1) ? cm1[j - DCH - 1] : NEGV;  // chunks [0 .. j-DCH-1]
    const int b1 = (j - DCH) * PADS;
#pragma unroll
    for (int i = 0; i < CH; i++) {
      float pre_s = NEGV;
      if (j >= DCH) { prerun = fmaxf(prerun, P1s[b1 + i]); pre_s = prerun; }
      float suf_s = (j <= NTH - 1 - DCH) ? rs[i] : NEGV;
      int t = base + i;
      if (pre_s > NEGH && suf_s > NEGH && t < len) {
        float pa = frcp(1.f + __expf(-z[i]));
        float sc = (pre_s * pa) * suf_s;
        if (sc > best) { best = sc; bidx = t; }   // strict > keeps first occurrence
      }
    }
  }
#pragma unroll
  for (int off = 32; off; off >>= 1) {
    float ov = __shfl_down(best, off);
    int   oi = __shfl_down(bidx, off);
    amax_comb(best, bidx, ov, oi);
  }
  if (lane == 0) { redv[wv] = best; redi[wv] = bidx; }
  __syncthreads();                   // B3
  int ac;
  {
    float v = redv[0]; int i = redi[0];
#pragma unroll
    for (int q = 1; q < NW; q++) amax_comb(v, i, redv[q], redi[q]);
    ac = i;
  }

  // ---------- phase 4: s1 = argmax p1m on [0, ac-16]; s2 = argmax p2m on [ac+16, T) ----
  {
    float v1 = NEGV; int i1 = 0;
    float v2 = NEGV; int i2 = 0;
    const int e1   = ac - DELTA;
    const int s2lo = ac + DELTA;
#pragma unroll
    for (int k = 0; k < CH; k++) {
      int t = base + k;
      float p1v = p1r[k];
      if (t <= e1 && p1v > v1) { v1 = p1v; i1 = t; }
      float p2v = (p1v > NEGH) ? 1.f - p1v : NEGV;
      if (t >= s2lo && p2v > v2) { v2 = p2v; i2 = t; }
    }
#pragma unroll
    for (int off = 32; off; off >>= 1) {
      float ov1 = __shfl_down(v1, off); int oi1 = __shfl_down(i1, off);
      amax_comb(v1, i1, ov1, oi1);
      float ov2 = __shfl_down(v2, off); int oi2 = __shfl_down(i2, off);
      amax_comb(v2, i2, ov2, oi2);
    }
    if (lane == 0) { redv2[wv] = v1; redi2[wv] = i1; redv3[wv] = v2; redi3[wv] = i2; }
  }

  // ---------- phase 5: full action loss from registers + block sum + output ----------
  // valid & |t-ac|<=4 -> 10*softplus(-z); valid else -> softplus(z); invalid -> 0
  float sp_part = 0.f;
#pragma unroll
  for (int k = 0; k < CH; k++) {
    int t = base + k;
    if (t < len) {
      float zi = z[k];
      float b0 = fmaxf(zi, 0.f) + __logf(1.f + __expf(-fabsf(zi)));  // softplus(z)
      int d = t - ac;
      sp_part += (d >= -4 && d <= 4) ? 10.f * (b0 - zi) : b0;
    }
  }
  float s = sp_part;
#pragma unroll
  for (int off = 32; off; off >>= 1) s += __shfl_down(s, off);
  if (lane == 0) wag1[wv] = s;   // safe: last wag1 read was before B3
  __syncthreads();                   // B4
  if (tid == 0) {
    float tot = 0.f;
#pragma unroll
    for (int q = 0; q < NW; q++) tot += wag1[q];

    float sv_1 = redv2[0]; int s1 = redi2[0];
    float sv_2 = redv3[0]; int s2 = redi3[0];
    for (int q = 1; q < NW; q++) {
      amax_comb(sv_1, s1, redv2[q], redi2[q]);
      amax_comb(sv_2, s2, redv3[q], redi3[q]);
    }
    // state CE: -log_softmax[s1,0] = softplus(l1-l0); -log_softmax[s2,1] = softplus(l0-l1)
    float2 q1 = *reinterpret_cast<const float2*>(srow + 2 * (size_t)s1);
    float2 q2 = *reinterpret_cast<const float2*>(srow + 2 * (size_t)s2);
    float d1 = q1.y - q1.x;
    float loss1 = fmaxf(d1, 0.f) + __logf(1.f + __expf(-fabsf(d1)));
    float d2 = q2.x - q2.y;
    float loss2 = fmaxf(d2, 0.f) + __logf(1.f + __expf(-fabsf(d2)));

    float w = vls[b];
    ws[2 * (size_t)b]     = w * (loss1 + loss2);
    ws[2 * (size_t)b + 1] = 0.2f * w * tot;
  }
}

__global__ void lftc_reduce(const float* __restrict__ ws, float* __restrict__ out, int B) {
  __shared__ float a0[4], a1[4];
  const int tid  = threadIdx.x;
  const int lane = tid & 63;
  const int wv   = tid >> 6;
  float s0 = 0.f, s1 = 0.f;
  const float2* w2 = reinterpret_cast<const float2*>(ws);
  for (int i = tid; i < B; i += 256) {
    float2 p = w2[i];
    s0 += p.x;
    s1 += p.y;
  }
#pragma unroll
  for (int off = 32; off; off >>= 1) {
    s0 += __shfl_down(s0, off);
    s1 += __shfl_down(s1, off);
  }
  if (lane == 0) { a0[wv] = s0; a1[wv] = s1; }
  __syncthreads();
  if (tid == 0) {
    out[0] = a0[0] + a0[1] + a0[2] + a0[3];
    out[1] = a1[0] + a1[1] + a1[2] + a1[3];
  }
}

extern "C" void kernel_launch(void* const* d_in, const int* in_sizes, int n_in,
                              void* d_out, int out_size, void* d_ws, size_t ws_size,
                              hipStream_t stream) {
  const float* s1s2 = (const float*)d_in[0];
  const float* act  = (const float*)d_in[1];
  const int*   lens = (const int*)d_in[2];
  const float* vls  = (const float*)d_in[3];
  float* out = (float*)d_out;
  float* ws  = (float*)d_ws;

  const int B = in_sizes[2];   // lens has B elements; T fixed at 4096

  lftc_main<<<B, NTH, 0, stream>>>(s1s2, act, lens, vls, ws);
  lftc_reduce<<<1, 256, 0, stream>>>(ws, out, B);
}

// Round 6
// 98.869 us; speedup vs baseline: 1.1595x; 1.0984x over previous
//
#include <hip/hip_runtime.h>
#include <math.h>

// One block (512 threads = 8 waves) per video row. T = 4096 = 512 chunks x 8.
// DELTA=16 = 2 chunks. Thread j owns chunk j (t in [8j,8j+8)).
// R6 changes vs R3: (1) launch_bounds(512,6) -> 3 blocks/CU (24 waves/CU), register
// diet to fit 85-VGPR cap (p1r dropped, own chunk re-read from LDS in phase 4);
// (2) one barrier removed: phase 3 computes its two cummax entries inline from raw
// per-thread wave-scans + wave totals; (3) no tid0 global tail: dr[i]=l1-l0 kept in
// registers, s1/s2 owners compute softplus(+/-dr) locally and write ws slots directly.
// ws layout: 4 floats/row {state@s1, state@s2, action, pad}; reduce kernel sums.
// (R4 lesson: do NOT accumulate d_out with same-address atomics — ~15us tail.)

#define T_LEN 4096
#define NTH   512
#define NW    8
#define CH    8
#define PADS  9        // chunk stride 9 words: 9 coprime 32 -> max 2-way/bank = free
#define DCH   2        // DELTA / CH
#define DELTA 16
#define NEGV  (-1e30f)
#define NEGH  (-5e29f)

__device__ __forceinline__ float frcp(float x) { return __builtin_amdgcn_rcpf(x); }

__device__ __forceinline__ void amax_comb(float& v, int& i, float ov, int oi) {
  // argmax, first-occurrence (smallest index) tie-break — matches jnp.argmax
  if (ov > v || (ov == v && oi < i)) { v = ov; i = oi; }
}

__global__ __launch_bounds__(NTH, 6) void lftc_main(
    const float* __restrict__ s1s2,  // [B, T, 2]
    const float* __restrict__ act,   // [B, T]
    const int*   __restrict__ lens,  // [B]
    const float* __restrict__ vls,   // [B]
    float* __restrict__ ws)          // [B, 4]: {state_s1, state_s2, action, pad}
{
  __shared__ float P1s[NTH * PADS];  // masked p1 (p2 = 1-p1 where valid)
  __shared__ float cr1[NTH];         // raw within-wave inclusive prefix-max (p1 side)
  __shared__ float cr2[NTH];         // raw within-wave inclusive suffix-max (p2 side)
  __shared__ float wag1[NW], wag2[NW];
  __shared__ float redv[NW];  __shared__ int redi[NW];   // ac argmax
  __shared__ float redv2[NW]; __shared__ int redi2[NW];  // s1 argmax
  __shared__ float redv3[NW]; __shared__ int redi3[NW];  // s2 argmax
  __shared__ float wact[NW];

  const int b    = blockIdx.x;
  const int tid  = threadIdx.x;
  const int lane = tid & 63;
  const int wv   = tid >> 6;
  const int len  = lens[b];
  const float w  = vls[b];

  const float* __restrict__ srow = s1s2 + (size_t)b * T_LEN * 2;
  const float* __restrict__ zrow = act  + (size_t)b * T_LEN;

  const int j    = tid;
  const int base = j * CH;

  // ---------- phase 1: load, softmax via single exp, mask, publish to LDS ----------
  float4 sv0, sv1, sv2, sv3, zva, zvb;
  {
    const float4* sp4 = reinterpret_cast<const float4*>(srow + 2 * base);
    sv0 = sp4[0]; sv1 = sp4[1]; sv2 = sp4[2]; sv3 = sp4[3];
    const float4* zp4 = reinterpret_cast<const float4*>(zrow + base);
    zva = zp4[0]; zvb = zp4[1];
  }
  float z[CH]  = {zva.x, zva.y, zva.z, zva.w, zvb.x, zvb.y, zvb.z, zvb.w};
  float dr[CH] = {sv0.y - sv0.x, sv0.w - sv0.z, sv1.y - sv1.x, sv1.w - sv1.z,
                  sv2.y - sv2.x, sv2.w - sv2.z, sv3.y - sv3.x, sv3.w - sv3.z};

  float m1 = NEGV, m2 = NEGV;
#pragma unroll
  for (int i = 0; i < CH; i++) {
    float p   = frcp(1.f + __expf(dr[i]));     // p1 = softmax[...,0] = 1/(1+e^(l1-l0))
    bool  v   = (base + i) < len;
    float p1m = v ? p : NEGV;
    float p2m = v ? 1.f - p : NEGV;
    P1s[j * PADS + i] = p1m;
    m1 = fmaxf(m1, p1m);
    m2 = fmaxf(m2, p2m);
  }

  // ---------- phase 2: within-wave scans; publish raw scans + wave totals ----------
  {
    float pm = m1;
#pragma unroll
    for (int off = 1; off < 64; off <<= 1) {
      float o = __shfl_up(pm, off);
      if (lane >= off) pm = fmaxf(pm, o);
    }
    float sm = m2;
#pragma unroll
    for (int off = 1; off < 64; off <<= 1) {
      float o = __shfl_down(sm, off);
      if (lane + off < 64) sm = fmaxf(sm, o);
    }
    cr1[tid] = pm;                   // raw: max over chunks [wave_start .. j]
    cr2[tid] = sm;                   // raw: max over chunks [j .. wave_end]
    if (lane == 63) wag1[wv] = pm;   // wave total (prefix side)
    if (lane == 0)  wag2[wv] = sm;   // wave total (suffix side)
  }
  __syncthreads();                   // B1: publishes P1s, cr1/cr2, wave totals

  // ---------- phase 3: score[t] = pre[t-16]*sigmoid(z[t])*suf[t+16]; argmax -> ac ----
  float best = NEGV;
  int   bidx = base;    // all-masked rows reduce to index 0 (matches jnp.argmax)
  {
    float rs[CH];       // suf_s for this chunk: reverse partial over chunk j+DCH
    if (j <= NTH - 1 - DCH) {
      float run = NEGV;
      if (j + DCH + 1 <= NTH - 1) {
        int q = j + DCH + 1;         // inclusive suffix max over chunks [q .. 511]
        run = cr2[q];
        int wq = q >> 6;
#pragma unroll
        for (int u = 1; u < NW; u++) if (u > wq) run = fmaxf(run, wag2[u]);
      }
      const int b2 = (j + DCH) * PADS;
#pragma unroll
      for (int i = CH - 1; i >= 0; --i) {
        float p1n = P1s[b2 + i];
        float p2n = (p1n > NEGH) ? 1.f - p1n : NEGV;
        run = fmaxf(run, p2n);
        rs[i] = run;
      }
    }
    float prerun = NEGV;
    if (j >= DCH + 1) {
      int q = j - DCH - 1;           // inclusive prefix max over chunks [0 .. q]
      prerun = cr1[q];
      int wq = q >> 6;
#pragma unroll
      for (int u = 0; u < NW - 1; u++) if (u < wq) prerun = fmaxf(prerun, wag1[u]);
    }
    const int b1 = (j - DCH) * PADS;
#pragma unroll
    for (int i = 0; i < CH; i++) {
      float pre_s = NEGV;
      if (j >= DCH) { prerun = fmaxf(prerun, P1s[b1 + i]); pre_s = prerun; }
      float suf_s = (j <= NTH - 1 - DCH) ? rs[i] : NEGV;
      int t = base + i;
      if (pre_s > NEGH && suf_s > NEGH && t < len) {
        float pa = frcp(1.f + __expf(-z[i]));
        float sc = (pre_s * pa) * suf_s;
        if (sc > best) { best = sc; bidx = t; }   // strict > keeps first occurrence
      }
    }
  }
#pragma unroll
  for (int off = 32; off; off >>= 1) {
    float ov = __shfl_down(best, off);
    int   oi = __shfl_down(bidx, off);
    amax_comb(best, bidx, ov, oi);
  }
  if (lane == 0) { redv[wv] = best; redi[wv] = bidx; }
  __syncthreads();                   // B2
  int ac;
  {
    float v = redv[0]; int i = redi[0];
#pragma unroll
    for (int q = 1; q < NW; q++) amax_comb(v, i, redv[q], redi[q]);
    ac = i;
  }

  // ---------- phase 4: s1 = argmax p1m on [0, ac-16]; s2 = argmax p2m on [ac+16, T) ----
  {
    float v1 = NEGV; int i1 = 0;
    float v2 = NEGV; int i2 = 0;
    const int e1   = ac - DELTA;
    const int s2lo = ac + DELTA;
    const int bj   = j * PADS;
#pragma unroll
    for (int k = 0; k < CH; k++) {
      int t = base + k;
      float p1v = P1s[bj + k];                       // re-read own chunk (reg diet)
      if (t <= e1 && p1v > v1) { v1 = p1v; i1 = t; }
      float p2v = (p1v > NEGH) ? 1.f - p1v : NEGV;
      if (t >= s2lo && p2v > v2) { v2 = p2v; i2 = t; }
    }
#pragma unroll
    for (int off = 32; off; off >>= 1) {
      float ov1 = __shfl_down(v1, off); int oi1 = __shfl_down(i1, off);
      amax_comb(v1, i1, ov1, oi1);
      float ov2 = __shfl_down(v2, off); int oi2 = __shfl_down(i2, off);
      amax_comb(v2, i2, ov2, oi2);
    }
    if (lane == 0) { redv2[wv] = v1; redi2[wv] = i1; redv3[wv] = v2; redi3[wv] = i2; }
  }

  // ---------- phase 5: action loss from registers + block sum ----------
  // valid & |t-ac|<=4 -> 10*softplus(-z); valid else -> softplus(z); invalid -> 0
  float sp_part = 0.f;
#pragma unroll
  for (int k = 0; k < CH; k++) {
    int t = base + k;
    if (t < len) {
      float zi = z[k];
      float b0 = fmaxf(zi, 0.f) + __logf(1.f + __expf(-fabsf(zi)));  // softplus(z)
      int d = t - ac;
      sp_part += (d >= -4 && d <= 4) ? 10.f * (b0 - zi) : b0;
    }
  }
#pragma unroll
  for (int off = 32; off; off >>= 1) sp_part += __shfl_down(sp_part, off);
  if (lane == 0) wact[wv] = sp_part;
  __syncthreads();                   // B3: publishes redv2/3, wact

  // ---------- phase 6: owners write state losses; tid0 writes action ----------
  {
    float sv_1 = redv2[0]; int s1 = redi2[0];
    float sv_2 = redv3[0]; int s2 = redi3[0];
#pragma unroll
    for (int q = 1; q < NW; q++) {
      amax_comb(sv_1, s1, redv2[q], redi2[q]);
      amax_comb(sv_2, s2, redv3[q], redi3[q]);
    }
    // state CE: -log_softmax[s1,0] = softplus(l1-l0) = softplus(dr);
    //           -log_softmax[s2,1] = softplus(l0-l1) = softplus(-dr)
    if (j == (s1 >> 3)) {
      float d1 = dr[s1 & 7];
      float loss1 = fmaxf(d1, 0.f) + __logf(1.f + __expf(-fabsf(d1)));
      ws[4 * (size_t)b + 0] = w * loss1;
    }
    if (j == (s2 >> 3)) {
      float d2 = -dr[s2 & 7];
      float loss2 = fmaxf(d2, 0.f) + __logf(1.f + __expf(-fabsf(d2)));
      ws[4 * (size_t)b + 1] = w * loss2;
    }
    if (tid == 0) {
      float tot = 0.f;
#pragma unroll
      for (int q = 0; q < NW; q++) tot += wact[q];
      ws[4 * (size_t)b + 2] = 0.2f * w * tot;
    }
  }
}

__global__ void lftc_reduce(const float* __restrict__ ws, float* __restrict__ out, int B) {
  __shared__ float a0[4], a1[4];
  const int tid  = threadIdx.x;
  const int lane = tid & 63;
  const int wv   = tid >> 6;
  float s0 = 0.f, s1 = 0.f;
  const float4* w4 = reinterpret_cast<const float4*>(ws);
  for (int i = tid; i < B; i += 256) {
    float4 p = w4[i];
    s0 += p.x + p.y;
    s1 += p.z;
  }
#pragma unroll
  for (int off = 32; off; off >>= 1) {
    s0 += __shfl_down(s0, off);
    s1 += __shfl_down(s1, off);
  }
  if (lane == 0) { a0[wv] = s0; a1[wv] = s1; }
  __syncthreads();
  if (tid == 0) {
    out[0] = a0[0] + a0[1] + a0[2] + a0[3];
    out[1] = a1[0] + a1[1] + a1[2] + a1[3];
  }
}

extern "C" void kernel_launch(void* const* d_in, const int* in_sizes, int n_in,
                              void* d_out, int out_size, void* d_ws, size_t ws_size,
                              hipStream_t stream) {
  const float* s1s2 = (const float*)d_in[0];
  const float* act  = (const float*)d_in[1];
  const int*   lens = (const int*)d_in[2];
  const float* vls  = (const float*)d_in[3];
  float* out = (float*)d_out;
  float* ws  = (float*)d_ws;

  const int B = in_sizes[2];   // lens has B elements; T fixed at 4096

  lftc_main<<<B, NTH, 0, stream>>>(s1s2, act, lens, vls, ws);
  lftc_reduce<<<1, 256, 0, stream>>>(ws, out, B);
}